// Round 1
// baseline (520.274 us; speedup 1.0000x reference)
//
#include <hip/hip_runtime.h>
#include <math.h>

// Problem constants (from reference setup_inputs)
static constexpr int N_ = 4;     // batch
static constexpr int R_ = 256;   // rois per image
static constexpr int C_ = 1024;  // channels
static constexpr int H_ = 50;    // feature map H
static constexpr int W_ = 50;    // feature map W
static constexpr int P_ = 7;     // pooled output size
static constexpr int HW_ = H_ * W_;
static constexpr int TOTAL = N_ * R_ * C_ * P_ * P_;  // 51,380,224 (< 2^31)

__device__ __forceinline__ float sample_bilinear(const float* __restrict__ plane,
                                                 float py, float px) {
    float y0f = floorf(py), x0f = floorf(px);
    int y0 = (int)y0f, x0 = (int)x0f;
    float wy1 = py - y0f, wy0 = 1.0f - wy1;
    float wx1 = px - x0f, wx0 = 1.0f - wx1;
    int y1 = y0 + 1, x1 = x0 + 1;

    // zero-padding validity per corner (matches reference semantics)
    float my0 = (y0 >= 0 && y0 <= H_ - 1) ? 1.0f : 0.0f;
    float my1 = (y1 >= 0 && y1 <= H_ - 1) ? 1.0f : 0.0f;
    float mx0 = (x0 >= 0 && x0 <= W_ - 1) ? 1.0f : 0.0f;
    float mx1 = (x1 >= 0 && x1 <= W_ - 1) ? 1.0f : 0.0f;

    int yc0 = min(max(y0, 0), H_ - 1);
    int yc1 = min(max(y1, 0), H_ - 1);
    int xc0 = min(max(x0, 0), W_ - 1);
    int xc1 = min(max(x1, 0), W_ - 1);

    float v00 = plane[yc0 * W_ + xc0] * (my0 * mx0);
    float v01 = plane[yc0 * W_ + xc1] * (my0 * mx1);
    float v10 = plane[yc1 * W_ + xc0] * (my1 * mx0);
    float v11 = plane[yc1 * W_ + xc1] * (my1 * mx1);

    float top = fmaf(v01, wx1, v00 * wx0);
    float bot = fmaf(v11, wx1, v10 * wx0);
    return fmaf(bot, wy1, top * wy0);
}

__global__ __launch_bounds__(256) void roipool_kernel(
    const float* __restrict__ rois,
    const float* __restrict__ fm,
    float* __restrict__ out) {

    int idx = blockIdx.x * 256 + threadIdx.x;
    if (idx >= TOTAL) return;

    // out layout: [N, R, C, 7, 7]; j fastest
    int pj = idx % P_;
    int t1 = idx / P_;
    int pi = t1 % P_;
    int t2 = t1 / P_;
    int c  = t2 % C_;
    int t3 = t2 / C_;
    int r  = t3 % R_;
    int n  = t3 / R_;

    // roi: (y, x, h, w) in image coords; stride 16
    const float4 roi = reinterpret_cast<const float4*>(rois)[n * R_ + r];
    float y1 = roi.x * 0.0625f;
    float x1 = roi.y * 0.0625f;
    float y2 = (roi.x + roi.z) * 0.0625f;
    float x2 = (roi.y + roi.w) * 0.0625f;
    // sample grid: px_k = x1 + k*(x2-x1)/13, k = 0..13 (exact simplification of
    // the reference's theta/linspace/denorm chain; continuous bilinear => safe)
    float sy = (y2 - y1) * (1.0f / 13.0f);
    float sx = (x2 - x1) * (1.0f / 13.0f);

    const float* plane = fm + (size_t)(n * C_ + c) * HW_;

    float best = -INFINITY;
#pragma unroll
    for (int dy = 0; dy < 2; ++dy) {
        float py = y1 + sy * (float)(2 * pi + dy);
#pragma unroll
        for (int dx = 0; dx < 2; ++dx) {
            float px = x1 + sx * (float)(2 * pj + dx);
            best = fmaxf(best, sample_bilinear(plane, py, px));
        }
    }
    out[idx] = best;
}

extern "C" void kernel_launch(void* const* d_in, const int* in_sizes, int n_in,
                              void* d_out, int out_size, void* d_ws, size_t ws_size,
                              hipStream_t stream) {
    const float* rois = (const float*)d_in[0];        // [4,256,4]
    const float* fm   = (const float*)d_in[1];        // [4,1024,50,50]
    float* out        = (float*)d_out;                // [4,256,1024,7,7]

    int blocks = (TOTAL + 255) / 256;  // 200,704
    roipool_kernel<<<blocks, 256, 0, stream>>>(rois, fm, out);
}

// Round 2
// 316.951 us; speedup vs baseline: 1.6415x; 1.6415x over previous
//
#include <hip/hip_runtime.h>
#include <math.h>

// Problem constants (from reference setup_inputs)
static constexpr int N_ = 4, R_ = 256, C_ = 1024, H_ = 50, W_ = 50, P_ = 7;
static constexpr int HW_ = H_ * W_;
static constexpr int PP_ = P_ * P_;          // 49 output pixels per (roi, channel)
static constexpr int CH_PER_WAVE = 64;       // 16 waves per roi x 64 ch = 1024

// Per-axis geometry for the two sub-samples of one pooled output cell.
// Sample spacing < 1 pixel guarantees both samples' corners lie in a
// 3-wide window starting at floor(p0). Validity (zero-padding) is folded
// into the weights; indices are clamped for safe (masked-out) loads.
__device__ __forceinline__ void axis_geom(float p0, float p1, int L,
                                          int idx[3], float wA[3], float wB[3]) {
    float f0 = floorf(p0); int i0 = (int)f0; float a0 = p0 - f0;
    float f1 = floorf(p1); int i1 = (int)f1; float a1 = p1 - f1;
    const bool o = (i1 > i0);
    wA[0] = 1.0f - a0; wA[1] = a0; wA[2] = 0.0f;
    wB[0] = o ? 0.0f : (1.0f - a1);
    wB[1] = o ? (1.0f - a1) : a1;
    wB[2] = o ? a1 : 0.0f;
#pragma unroll
    for (int j = 0; j < 3; ++j) {
        int ij = i0 + j;
        if (ij < 0 || ij > L - 1) { wA[j] = 0.0f; wB[j] = 0.0f; }
        idx[j] = min(max(ij, 0), L - 1);
    }
}

// Block = 256 threads = 4 waves. Grid = N*R*4 blocks.
// Block (n, r, q); wave w handles channels (q*4+w)*64 .. +63.
// Lane = output pixel (49 active / 64).
__global__ __launch_bounds__(256) void roipool_kernel(
    const float* __restrict__ rois,
    const float* __restrict__ fm,
    float* __restrict__ out) {

    const int b  = blockIdx.x;
    const int q  = b & 3;
    const int nr = b >> 2;           // n*R + r
    const int n  = nr >> 8;          // R_ = 256
    const int lane = threadIdx.x & 63;
    int wv = threadIdx.x >> 6;
    wv = __builtin_amdgcn_readfirstlane(wv);   // force wave-uniform (SGPR) base
    const int c0 = (q * 4 + wv) * CH_PER_WAVE;

    // roi: (y, x, h, w) in image coords; stride 16
    const float4 roi = reinterpret_cast<const float4*>(rois)[nr];
    const float y1 = roi.x * 0.0625f;
    const float x1 = roi.y * 0.0625f;
    const float y2 = (roi.x + roi.z) * 0.0625f;
    const float x2 = (roi.y + roi.w) * 0.0625f;
    const float sy = (y2 - y1) * (1.0f / 13.0f);
    const float sx = (x2 - x1) * (1.0f / 13.0f);

    const int pi = lane / 7;         // idle lanes (>=49) get harmless geometry
    const int pj = lane - pi * 7;

    const float py0 = y1 + sy * (float)(2 * pi);
    const float py1 = y1 + sy * (float)(2 * pi + 1);
    const float px0 = x1 + sx * (float)(2 * pj);
    const float px1 = x1 + sx * (float)(2 * pj + 1);

    int ry[3]; float wyA[3], wyB[3];
    axis_geom(py0, py1, H_, ry, wyA, wyB);
    int cx[3]; float wxA[3], wxB[3];
    axis_geom(px0, px1, W_, cx, wxA, wxB);

    // 9 element offsets into the 50x50 plane (per-lane, constant over channels)
    const int r0 = ry[0] * W_, r1 = ry[1] * W_, r2 = ry[2] * W_;
    const int o00 = r0 + cx[0], o01 = r0 + cx[1], o02 = r0 + cx[2];
    const int o10 = r1 + cx[0], o11 = r1 + cx[1], o12 = r1 + cx[2];
    const int o20 = r2 + cx[0], o21 = r2 + cx[1], o22 = r2 + cx[2];

    const float* __restrict__ plane = fm + (size_t)(n * C_ + c0) * HW_;
    float* __restrict__ po = out + ((size_t)nr * C_ + c0) * PP_ + lane;
    const bool active = lane < PP_;

#pragma unroll 4
    for (int k = 0; k < CH_PER_WAVE; ++k) {
        const float v00 = plane[o00], v01 = plane[o01], v02 = plane[o02];
        const float v10 = plane[o10], v11 = plane[o11], v12 = plane[o12];
        const float v20 = plane[o20], v21 = plane[o21], v22 = plane[o22];

        // combine rows for each of the two y-samples
        const float tA0 = fmaf(wyA[2], v20, fmaf(wyA[1], v10, wyA[0] * v00));
        const float tA1 = fmaf(wyA[2], v21, fmaf(wyA[1], v11, wyA[0] * v01));
        const float tA2 = fmaf(wyA[2], v22, fmaf(wyA[1], v12, wyA[0] * v02));
        const float tB0 = fmaf(wyB[2], v20, fmaf(wyB[1], v10, wyB[0] * v00));
        const float tB1 = fmaf(wyB[2], v21, fmaf(wyB[1], v11, wyB[0] * v01));
        const float tB2 = fmaf(wyB[2], v22, fmaf(wyB[1], v12, wyB[0] * v02));

        // combine columns for the two x-samples -> 4 bilinear samples
        const float s00 = fmaf(wxA[2], tA2, fmaf(wxA[1], tA1, wxA[0] * tA0));
        const float s01 = fmaf(wxB[2], tA2, fmaf(wxB[1], tA1, wxB[0] * tA0));
        const float s10 = fmaf(wxA[2], tB2, fmaf(wxA[1], tB1, wxA[0] * tB0));
        const float s11 = fmaf(wxB[2], tB2, fmaf(wxB[1], tB1, wxB[0] * tB0));

        const float best = fmaxf(fmaxf(s00, s01), fmaxf(s10, s11));
        if (active) *po = best;

        plane += HW_;
        po += PP_;
    }
}

extern "C" void kernel_launch(void* const* d_in, const int* in_sizes, int n_in,
                              void* d_out, int out_size, void* d_ws, size_t ws_size,
                              hipStream_t stream) {
    const float* rois = (const float*)d_in[0];        // [4,256,4]
    const float* fm   = (const float*)d_in[1];        // [4,1024,50,50]
    float* out        = (float*)d_out;                // [4,256,1024,7,7]

    const int blocks = N_ * R_ * 4;                   // 4096
    roipool_kernel<<<blocks, 256, 0, stream>>>(rois, fm, out);
}

// Round 4
// 122.816 us; speedup vs baseline: 4.2362x; 2.5807x over previous
//
#include <hip/hip_runtime.h>
#include <math.h>

// Problem constants (from reference setup_inputs)
static constexpr int N_ = 4, R_ = 256, C_ = 1024, H_ = 50, W_ = 50, P_ = 7;
static constexpr int HW_ = H_ * W_;
static constexpr int PP_ = P_ * P_;          // 49 output pixels per (roi, channel)
static constexpr int CH_ = 64;               // channels per wave; 16 waves per roi

typedef const __attribute__((address_space(1))) void* gaddr_t;
typedef __attribute__((address_space(3))) void* laddr_t;

__device__ __forceinline__ void ld_lds4(const float* g, float* l) {
    // async global->LDS, 4B per lane, dest = wave-uniform base + lane*4
    __builtin_amdgcn_global_load_lds((gaddr_t)g, (laddr_t)l, 4, 0, 0);
}

// Counted waits (T4): all but the N newest VMEM ops drained. Correct under
// either vmcnt-store-counting semantics because N==4 == loads per STAGE.
#define VMWAIT4()  asm volatile("s_waitcnt vmcnt(4)" ::: "memory")
#define LGKMWAIT() asm volatile("s_waitcnt lgkmcnt(0)" ::: "memory")

// Window-relative per-axis geometry for the two sub-samples of one pooled cell.
// Sample spacing < 1 px => both samples' corners lie in a 3-wide window at
// rel0 = floor(p0) - base. Zero-padding validity folded into weights.
__device__ __forceinline__ void axis_rel(float p0, float p1, int base, int L,
                                         int& rel0, float wA[3], float wB[3]) {
    float f0 = floorf(p0); int i0 = (int)f0; float a0 = p0 - f0;
    float f1 = floorf(p1); int i1 = (int)f1; float a1 = p1 - f1;
    const bool o = (i1 > i0);
    wA[0] = 1.0f - a0; wA[1] = a0; wA[2] = 0.0f;
    wB[0] = o ? 0.0f : (1.0f - a1);
    wB[1] = o ? (1.0f - a1) : a1;
    wB[2] = o ? a1 : 0.0f;
#pragma unroll
    for (int j = 0; j < 3; ++j) {
        int ij = i0 + j;
        if (ij < 0 || ij > L - 1) { wA[j] = 0.0f; wB[j] = 0.0f; }
    }
    rel0 = min(max(i0 - base, 0), 13);   // window-relative; max gather idx 221+34=255
}

__device__ __forceinline__ float gather9(const float* __restrict__ cur, int gb,
                                         const float wyA[3], const float wyB[3],
                                         const float wxA[3], const float wxB[3]) {
    const float v00 = cur[gb + 0],  v01 = cur[gb + 1],  v02 = cur[gb + 2];
    const float v10 = cur[gb + 16], v11 = cur[gb + 17], v12 = cur[gb + 18];
    const float v20 = cur[gb + 32], v21 = cur[gb + 33], v22 = cur[gb + 34];

    const float tA0 = fmaf(wyA[2], v20, fmaf(wyA[1], v10, wyA[0] * v00));
    const float tA1 = fmaf(wyA[2], v21, fmaf(wyA[1], v11, wyA[0] * v01));
    const float tA2 = fmaf(wyA[2], v22, fmaf(wyA[1], v12, wyA[0] * v02));
    const float tB0 = fmaf(wyB[2], v20, fmaf(wyB[1], v10, wyB[0] * v00));
    const float tB1 = fmaf(wyB[2], v21, fmaf(wyB[1], v11, wyB[0] * v01));
    const float tB2 = fmaf(wyB[2], v22, fmaf(wyB[1], v12, wyB[0] * v02));

    const float s00 = fmaf(wxA[2], tA2, fmaf(wxA[1], tA1, wxA[0] * tA0));
    const float s01 = fmaf(wxB[2], tA2, fmaf(wxB[1], tA1, wxB[0] * tA0));
    const float s10 = fmaf(wxA[2], tB2, fmaf(wxA[1], tB1, wxA[0] * tB0));
    const float s11 = fmaf(wxB[2], tB2, fmaf(wxB[1], tB1, wxB[0] * tB0));

    return fmaxf(fmaxf(s00, s01), fmaxf(s10, s11));
}

// Block = 4 waves. Grid = N*R*4. Block (nr, q); wave w -> channels (q*4+w)*64..+63.
// Lane = output pixel (49 active / 64). Per-wave double-buffered LDS patch,
// single-wave producer==consumer => counted vmcnt/lgkmcnt, no barriers.
__global__ __launch_bounds__(256) void roipool_kernel(
    const float* __restrict__ rois,
    const float* __restrict__ fm,
    float* __restrict__ out) {

    __shared__ float patch[4][2][256];   // per wave: 2 x (16x16) window, 8 KB total

    const int b  = blockIdx.x;
    const int q  = b & 3;
    const int nr = b >> 2;               // n*R + r
    const int n  = nr >> 8;              // R_ = 256
    const int lane = threadIdx.x & 63;
    const int wv = __builtin_amdgcn_readfirstlane(threadIdx.x >> 6);
    const int c0 = (q * 4 + wv) * CH_;

    // roi: (y, x, h, w) image coords; stride 16
    const float4 roi = reinterpret_cast<const float4*>(rois)[nr];
    const float y1 = roi.x * 0.0625f;
    const float x1 = roi.y * 0.0625f;
    const float y2 = (roi.x + roi.z) * 0.0625f;
    const float x2 = (roi.y + roi.w) * 0.0625f;
    const float sy = (y2 - y1) * (1.0f / 13.0f);
    const float sx = (x2 - x1) * (1.0f / 13.0f);

    const int y0 = max((int)floorf(y1), 0);   // window origin
    const int x0 = max((int)floorf(x1), 0);

    // Per-lane staging source offsets (constant across channels).
    // Lane l in round t loads patch word t*64+l = (dy,dx), clamped in-plane.
    int soff[4];
#pragma unroll
    for (int t = 0; t < 4; ++t) {
        const int idx = t * 64 + lane;
        const int dy = idx >> 4, dx = idx & 15;
        soff[t] = min(y0 + dy, H_ - 1) * W_ + min(x0 + dx, W_ - 1);
    }

    int pi = lane / 7;
    int pj = lane - pi * 7;
    const bool active = lane < PP_;
    if (!active) { pi = 0; pj = 0; }     // idle lanes mirror lane 0 -> LDS broadcast

    const float py0 = y1 + sy * (float)(2 * pi);
    const float py1 = y1 + sy * (float)(2 * pi + 1);
    const float px0 = x1 + sx * (float)(2 * pj);
    const float px1 = x1 + sx * (float)(2 * pj + 1);

    int ryr; float wyA[3], wyB[3];
    axis_rel(py0, py1, y0, H_, ryr, wyA, wyB);
    int cxr; float wxA[3], wxB[3];
    axis_rel(px0, px1, x0, W_, cxr, wxA, wxB);
    const int gb = ryr * 16 + cxr;       // word idx; +{0,1,2,16,17,18,32,33,34} <= 255

    const float* __restrict__ pbase = fm + (size_t)(n * C_ + c0) * HW_;
    float* __restrict__ po = out + ((size_t)nr * C_ + c0) * PP_ + lane;

    float* buf0 = &patch[wv][0][0];
    float* buf1 = &patch[wv][1][0];

#define STAGE(BUF, PL) do { \
        ld_lds4((PL) + soff[0], (BUF));       \
        ld_lds4((PL) + soff[1], (BUF) + 64);  \
        ld_lds4((PL) + soff[2], (BUF) + 128); \
        ld_lds4((PL) + soff[3], (BUF) + 192); \
    } while (0)

    // 2-ahead prefetch. Tail STAGEs clamp to the last channel (dummy restage)
    // so every iteration issues exactly 4 loads -> vmcnt counts stay uniform.
    STAGE(buf0, pbase);                       // ch 0
    STAGE(buf1, pbase + HW_);                 // ch 1

    for (int k = 0; k < CH_; k += 2) {
        VMWAIT4();                            // buf0(k) staged loads landed
        const float r0 = gather9(buf0, gb, wyA, wyB, wxA, wxB);
        if (active) po[(size_t)k * PP_] = r0;
        LGKMWAIT();                           // ds_reads of buf0 done -> safe to overwrite
        STAGE(buf0, pbase + (size_t)min(k + 2, CH_ - 1) * HW_);

        VMWAIT4();                            // buf1(k+1) staged loads landed
        const float r1 = gather9(buf1, gb, wyA, wyB, wxA, wxB);
        if (active) po[(size_t)(k + 1) * PP_] = r1;
        LGKMWAIT();
        STAGE(buf1, pbase + (size_t)min(k + 3, CH_ - 1) * HW_);
    }
#undef STAGE
}

extern "C" void kernel_launch(void* const* d_in, const int* in_sizes, int n_in,
                              void* d_out, int out_size, void* d_ws, size_t ws_size,
                              hipStream_t stream) {
    const float* rois = (const float*)d_in[0];        // [4,256,4]
    const float* fm   = (const float*)d_in[1];        // [4,1024,50,50]
    float* out        = (float*)d_out;                // [4,256,1024,7,7]

    const int blocks = N_ * R_ * 4;                   // 4096
    roipool_kernel<<<blocks, 256, 0, stream>>>(rois, fm, out);
}